// Round 6
// baseline (349.561 us; speedup 1.0000x reference)
//
#include <hip/hip_runtime.h>

#define NNODES 100000
#define NEDGES 800000
#define NGRAPHS 5000
#define FN 11
#define FE 4
#define H1C 32
#define H2C 16
#define MAXDEG 40
#define NPB 128          // nodes per gather block
#define LISTCAP 1280     // avg 1024 edges/block + 8 sigma

typedef __bf16 bf16x8 __attribute__((ext_vector_type(8)));
typedef float f32x4 __attribute__((ext_vector_type(4)));

// agg1[n,o] = c1_bias[o] + sum_i x[n,i]*c1_root[i,o]
__global__ __launch_bounds__(256) void k_init1(const float* __restrict__ x,
    const float* __restrict__ root, const float* __restrict__ bias,
    float* __restrict__ agg1) {
  int t = blockIdx.x * 256 + threadIdx.x;
  int n = t >> 5, o = t & 31;
  if (n >= NNODES) return;
  float acc = bias[o];
  #pragma unroll
  for (int i = 0; i < FN; i++) acc += x[n * FN + i] * root[i * H1C + o];
  agg1[n * H1C + o] = acc;
}

// Pre-swizzled bf16 B-fragments for conv1 MFMA (verified round 5).
__global__ __launch_bounds__(256) void k_prepB1(const float* __restrict__ w2,
    const float* __restrict__ b2, __bf16* __restrict__ B1s) {
  int t = blockIdx.x * 256 + threadIdx.x;
  if (t >= 2 * 12 * 64 * 8) return;
  int j = t & 7;
  int lane = (t >> 3) & 63;
  int rest = t >> 9;
  int step = rest % 12;
  int ot = rest / 12;
  int q = (lane >> 4) * 8 + j;
  int o = (lane & 15) + ot * 16;
  float v;
  if (step < 11) v = w2[q * (FN * H1C) + step * H1C + o];
  else v = (q < FN) ? b2[q * H1C + o] : 0.f;
  B1s[t] = (__bf16)v;
}

// conv1 edge pass via MFMA (verified round 5) + slot-table build.
__global__ __launch_bounds__(256) void k_edge1_mfma(
    const float* __restrict__ x, const int* __restrict__ ei,
    const float* __restrict__ ea, const float* __restrict__ w1,
    const float* __restrict__ b1, const __bf16* __restrict__ B1s,
    float* __restrict__ agg1, int* __restrict__ cnt, int* __restrict__ slots) {
  __shared__ __bf16 Bl[12288];
  __shared__ __bf16 h_sl[4][256][8];
  __shared__ __bf16 xs_sl[4][256][8];
  __shared__ int s_dst[256];
  int tid = threadIdx.x;
  {
    const int4* s = (const int4*)B1s;
    int4* d = (int4*)Bl;
    #pragma unroll
    for (int q = 0; q < 12; q++) d[tid + q * 256] = s[tid + q * 256];
  }
  int e = blockIdx.x * 256 + tid;   // NEDGES % 256 == 0
  int src = ei[e];
  int dstv = ei[NEDGES + e];
  s_dst[tid] = dstv;
  if (slots) {   // build dst -> edge slot table (conv2 gather uses it)
    int pos = atomicAdd(&cnt[dstv], 1);
    if (pos < MAXDEG) slots[dstv * MAXDEG + pos] = e;
  }
  float4 a4 = *reinterpret_cast<const float4*>(ea + e * 4);
  float h[32];
  #pragma unroll
  for (int k = 0; k < 32; k++) {
    float v = b1[k] + a4.x * w1[k] + a4.y * w1[32 + k] + a4.z * w1[64 + k] + a4.w * w1[96 + k];
    h[k] = v > 0.f ? v : 0.f;
  }
  #pragma unroll
  for (int s = 0; s < 4; s++) {
    bf16x8 t8;
    #pragma unroll
    for (int j = 0; j < 8; j++) t8[j] = (__bf16)h[s * 8 + j];
    *reinterpret_cast<bf16x8*>(&h_sl[s][tid][0]) = t8;
  }
  float xsv[FN];
  #pragma unroll
  for (int i = 0; i < FN; i++) xsv[i] = x[src * FN + i];
  #pragma unroll
  for (int s = 0; s < 4; s++) {
    bf16x8 t8;
    #pragma unroll
    for (int j = 0; j < 8; j++) {
      int k = s * 8 + j;
      t8[j] = (k < FN) ? (__bf16)xsv[k] : (__bf16)0.f;
    }
    *reinterpret_cast<bf16x8*>(&xs_sl[s][tid][0]) = t8;
  }
  __syncthreads();
  int lane = tid & 63;
  int w = tid >> 6;
  int halfk = lane >> 4;
  int er = lane & 15;
  #pragma unroll 1
  for (int g = 0; g < 4; g++) {
    int eb = w * 64 + g * 16;
    int el = eb + er;
    bf16x8 hs8 = *reinterpret_cast<const bf16x8*>(&h_sl[halfk][el][0]);
    bf16x8 xs8 = *reinterpret_cast<const bf16x8*>(&xs_sl[halfk][el][0]);
    float hsf[8];
    #pragma unroll
    for (int j = 0; j < 8; j++) hsf[j] = (float)hs8[j];
    f32x4 acc0 = {0.f, 0.f, 0.f, 0.f};
    f32x4 acc1 = {0.f, 0.f, 0.f, 0.f};
    {
      bf16x8 b0 = *reinterpret_cast<const bf16x8*>(&Bl[11 * 512 + lane * 8]);
      bf16x8 b1f = *reinterpret_cast<const bf16x8*>(&Bl[6144 + 11 * 512 + lane * 8]);
      acc0 = __builtin_amdgcn_mfma_f32_16x16x32_bf16(xs8, b0, acc0, 0, 0, 0);
      acc1 = __builtin_amdgcn_mfma_f32_16x16x32_bf16(xs8, b1f, acc1, 0, 0, 0);
    }
    #pragma unroll
    for (int i = 0; i < FN; i++) {
      float xscal = (float)xs_sl[i >> 3][el][i & 7];
      bf16x8 af;
      #pragma unroll
      for (int j = 0; j < 8; j++) af[j] = (__bf16)(xscal * hsf[j]);
      bf16x8 b0 = *reinterpret_cast<const bf16x8*>(&Bl[i * 512 + lane * 8]);
      bf16x8 b1f = *reinterpret_cast<const bf16x8*>(&Bl[6144 + i * 512 + lane * 8]);
      acc0 = __builtin_amdgcn_mfma_f32_16x16x32_bf16(af, b0, acc0, 0, 0, 0);
      acc1 = __builtin_amdgcn_mfma_f32_16x16x32_bf16(af, b1f, acc1, 0, 0, 0);
    }
    #pragma unroll
    for (int r = 0; r < 4; r++) {
      int d = s_dst[eb + halfk * 4 + r];
      atomicAdd(&agg1[d * H1C + er], acc0[r]);
      atomicAdd(&agg1[d * H1C + er + 16], acc1[r]);
    }
  }
}

// h1b = bf16(relu(agg1)); agg2[n,o] = c2_bias[o] + sum_i relu(agg1)[n,i]*c2_root[i,o]
__global__ __launch_bounds__(256) void k_mid(const float* __restrict__ agg1,
    const float* __restrict__ root2, const float* __restrict__ bias2,
    __bf16* __restrict__ h1b, float* __restrict__ agg2) {
  int t = blockIdx.x * 256 + threadIdx.x;
  int n = t >> 4, o = t & 15;
  if (n >= NNODES) return;
  float hv[32];
  #pragma unroll
  for (int i = 0; i < 32; i++) {
    float v = agg1[n * H1C + i];
    hv[i] = v > 0.f ? v : 0.f;
  }
  h1b[n * H1C + o] = (__bf16)hv[o];
  h1b[n * H1C + o + 16] = (__bf16)hv[o + 16];
  float acc = bias2[o];
  #pragma unroll
  for (int i = 0; i < 32; i++) acc += hv[i] * root2[i * H2C + o];
  agg2[n * H2C + o] = acc;
}

// Pre-swizzled bf16 B-fragments for conv2 MFMA.
__global__ __launch_bounds__(256) void k_prepB2(const float* __restrict__ w2,
    __bf16* __restrict__ B2s) {
  int t = blockIdx.x * 256 + threadIdx.x;
  if (t >= 32 * 64 * 8) return;
  int kk = t >> 9;
  int l = (t >> 3) & 63;
  int j = t & 7;
  int i = (l >> 4) * 8 + j;
  int o = l & 15;
  B2s[t] = (__bf16)w2[(kk * 32 + i) * H2C + o];
}

// conv2 node-centric gather: block owns NPB nodes, compacts incident edges
// from the slot table, runs the verified MFMA pipeline over 256-edge chunks,
// accumulates into LDS (no global atomics), fuses relu + global_add_pool.
__global__ __launch_bounds__(256) void k_gather2(
    const __bf16* __restrict__ h1b, const int* __restrict__ ei,
    const float* __restrict__ ea, const float* __restrict__ w1,
    const float* __restrict__ b1, const __bf16* __restrict__ B2s,
    const float* __restrict__ agg2base, const int* __restrict__ cnt,
    const int* __restrict__ slots, const int* __restrict__ batch,
    float* __restrict__ pooled) {
  __shared__ __bf16 Bl[16384];                 // 32 KB B-frags
  __shared__ __bf16 h_ch[256][40];             // 20 KB chunk h (rows 16B-aligned)
  __shared__ float accN[(NPB + 1) * H2C];      // 8.3 KB node accumulators (+trash row)
  __shared__ int s_list[LISTCAP];              // 5 KB edge ids
  __shared__ unsigned char s_dl[LISTCAP];      // 1.3 KB local node idx
  __shared__ int s_src_ch[256];
  __shared__ short s_dlc[256];
  int tid = threadIdx.x;
  {
    const int4* s = (const int4*)B2s;
    int4* d = (int4*)Bl;
    #pragma unroll
    for (int q = 0; q < 8; q++) d[q * 256 + tid] = s[q * 256 + tid];
  }
  int n0 = blockIdx.x * NPB;
  int n = n0 + tid;
  int deg = (tid < NPB && n < NNODES) ? cnt[n] : 0;
  if (deg > MAXDEG) deg = MAXDEG;
  int* s_scan = (int*)accN;   // reuse accN space for the scan
  s_scan[tid] = deg;
  __syncthreads();
  #pragma unroll
  for (int ofs = 1; ofs < 256; ofs <<= 1) {
    int v = (tid >= ofs) ? s_scan[tid - ofs] : 0;
    __syncthreads();
    s_scan[tid] += v;
    __syncthreads();
  }
  int start = s_scan[tid] - deg;
  int total = s_scan[255];
  __syncthreads();
  for (int q = 0; q < deg; q++) {
    int idx = start + q;
    s_list[idx] = slots[n * MAXDEG + q];
    s_dl[idx] = (unsigned char)tid;
  }
  #pragma unroll
  for (int q = 0; q < (NPB + 1) * H2C + 255; q += 256) {
    int i = q + tid;
    if (i < (NPB + 1) * H2C) accN[i] = 0.f;
  }
  __syncthreads();

  int lane = tid & 63;
  int w = tid >> 6;
  int halfk = lane >> 4;
  int er = lane & 15;
  int nch = (total + 255) >> 8;
  #pragma unroll 1
  for (int c = 0; c < nch; c++) {
    int idx = c * 256 + tid;
    if (idx < total) {
      int e = s_list[idx];
      s_src_ch[tid] = ei[e];
      s_dlc[tid] = s_dl[idx];
      float4 a4 = *reinterpret_cast<const float4*>(ea + e * 4);
      #pragma unroll
      for (int s = 0; s < 4; s++) {
        bf16x8 t8;
        #pragma unroll
        for (int j = 0; j < 8; j++) {
          int k = s * 8 + j;
          float v = b1[k] + a4.x * w1[k] + a4.y * w1[32 + k] + a4.z * w1[64 + k] + a4.w * w1[96 + k];
          t8[j] = (__bf16)(v > 0.f ? v : 0.f);
        }
        *reinterpret_cast<bf16x8*>(&h_ch[tid][s * 8]) = t8;
      }
    } else {
      s_src_ch[tid] = 0;
      s_dlc[tid] = NPB;   // trash row
      bf16x8 z = {};
      #pragma unroll
      for (int s = 0; s < 4; s++) *reinterpret_cast<bf16x8*>(&h_ch[tid][s * 8]) = z;
    }
    __syncthreads();
    #pragma unroll 1
    for (int g = 0; g < 4; g++) {
      int eb = w * 64 + g * 16;
      int el = eb + er;
      int sn = s_src_ch[el];
      bf16x8 hsb = *reinterpret_cast<const bf16x8*>(h1b + sn * H1C + halfk * 8);
      float hsf[8];
      #pragma unroll
      for (int j = 0; j < 8; j++) hsf[j] = (float)hsb[j];
      f32x4 acc = {0.f, 0.f, 0.f, 0.f};
      #pragma unroll
      for (int kk = 0; kk < 32; kk++) {
        float hscal = (float)h_ch[el][kk];
        bf16x8 bfrag = *reinterpret_cast<const bf16x8*>(Bl + (kk * 64 + lane) * 8);
        bf16x8 afrag;
        #pragma unroll
        for (int j = 0; j < 8; j++) afrag[j] = (__bf16)(hscal * hsf[j]);
        acc = __builtin_amdgcn_mfma_f32_16x16x32_bf16(afrag, bfrag, acc, 0, 0, 0);
      }
      #pragma unroll
      for (int r = 0; r < 4; r++) {
        int dlr = s_dlc[eb + halfk * 4 + r];
        atomicAdd(&accN[dlr * H2C + er], acc[r]);
      }
    }
    __syncthreads();
  }
  // epilogue: agg2 = base + acc, relu, pool (exclusive ownership, atomics only on pooled)
  #pragma unroll 1
  for (int p = 0; p < NPB / 16; p++) {
    int dl = p * 16 + (tid >> 4);
    int o = tid & 15;
    int nn = n0 + dl;
    if (nn < NNODES) {
      float val = accN[dl * H2C + o] + agg2base[nn * H2C + o];
      val = val > 0.f ? val : 0.f;
      atomicAdd(&pooled[batch[nn] * H2C + o], val);
    }
  }
}

// ---- fallback path (ws too small for slot table): round-5 kernels ----
__global__ __launch_bounds__(256) void k_edge2_mfma(
    const __bf16* __restrict__ h1b, const int* __restrict__ ei,
    const float* __restrict__ ea, const float* __restrict__ w1,
    const float* __restrict__ b1, const __bf16* __restrict__ B2s,
    float* __restrict__ agg2) {
  __shared__ __bf16 Bl[32 * 64 * 8];
  __shared__ float h_lds[256][33];
  __shared__ int s_src[256];
  __shared__ int s_dst[256];
  int tid = threadIdx.x;
  {
    const int4* s = (const int4*)B2s;
    int4* d = (int4*)Bl;
    #pragma unroll
    for (int q = 0; q < 8; q++) d[q * 256 + tid] = s[q * 256 + tid];
  }
  int e = blockIdx.x * 256 + tid;
  s_src[tid] = ei[e];
  s_dst[tid] = ei[NEDGES + e];
  float4 a4 = *reinterpret_cast<const float4*>(ea + e * 4);
  #pragma unroll
  for (int k = 0; k < 32; k++) {
    float v = b1[k] + a4.x * w1[k] + a4.y * w1[32 + k] + a4.z * w1[64 + k] + a4.w * w1[96 + k];
    h_lds[tid][k] = v > 0.f ? v : 0.f;
  }
  __syncthreads();
  int lane = tid & 63;
  int w = tid >> 6;
  int halfk = lane >> 4;
  int er = lane & 15;
  #pragma unroll 1
  for (int g = 0; g < 4; g++) {
    int eb = w * 64 + g * 16;
    int el = eb + er;
    int sn = s_src[el];
    bf16x8 hsb = *reinterpret_cast<const bf16x8*>(h1b + sn * H1C + halfk * 8);
    float hsf[8];
    #pragma unroll
    for (int j = 0; j < 8; j++) hsf[j] = (float)hsb[j];
    f32x4 acc = {0.f, 0.f, 0.f, 0.f};
    #pragma unroll
    for (int kk = 0; kk < 32; kk++) {
      float hscal = h_lds[el][kk];
      bf16x8 bfrag = *reinterpret_cast<const bf16x8*>(Bl + (kk * 64 + lane) * 8);
      bf16x8 afrag;
      #pragma unroll
      for (int j = 0; j < 8; j++) afrag[j] = (__bf16)(hscal * hsf[j]);
      acc = __builtin_amdgcn_mfma_f32_16x16x32_bf16(afrag, bfrag, acc, 0, 0, 0);
    }
    #pragma unroll
    for (int r = 0; r < 4; r++) {
      int d = s_dst[eb + halfk * 4 + r];
      atomicAdd(&agg2[d * H2C + er], acc[r]);
    }
  }
}

__global__ __launch_bounds__(256) void k_pool(const float* __restrict__ agg2,
    const int* __restrict__ batch, float* __restrict__ pooled) {
  int t = blockIdx.x * 256 + threadIdx.x;
  int n = t >> 4, o = t & 15;
  if (n >= NNODES) return;
  float v = agg2[n * H2C + o];
  v = v > 0.f ? v : 0.f;
  atomicAdd(&pooled[batch[n] * H2C + o], v);
}

// out[g] = relu(pooled[g]@fc1_w + fc1_b) @ out_w + out_b
__global__ __launch_bounds__(256) void k_head(const float* __restrict__ pooled,
    const float* __restrict__ fc1w, const float* __restrict__ fc1b,
    const float* __restrict__ outw, const float* __restrict__ outb,
    float* __restrict__ out) {
  int g = blockIdx.x * 256 + threadIdx.x;
  if (g >= NGRAPHS) return;
  float p[H2C];
  #pragma unroll
  for (int i = 0; i < H2C; i++) p[i] = pooled[g * H2C + i];
  float acc = outb[0];
  #pragma unroll
  for (int o = 0; o < H1C; o++) {
    float v = fc1b[o];
    #pragma unroll
    for (int i = 0; i < H2C; i++) v += p[i] * fc1w[i * H1C + o];
    v = v > 0.f ? v : 0.f;
    acc += v * outw[o];
  }
  out[g] = acc;
}

extern "C" void kernel_launch(void* const* d_in, const int* in_sizes, int n_in,
                              void* d_out, int out_size, void* d_ws, size_t ws_size,
                              hipStream_t stream) {
  const float* x      = (const float*)d_in[0];
  const int*   ei     = (const int*)d_in[1];
  const float* ea     = (const float*)d_in[2];
  const int*   batch  = (const int*)d_in[3];
  const float* c1w1   = (const float*)d_in[4];
  const float* c1b1   = (const float*)d_in[5];
  const float* c1w2   = (const float*)d_in[6];
  const float* c1b2   = (const float*)d_in[7];
  const float* c1root = (const float*)d_in[8];
  const float* c1bias = (const float*)d_in[9];
  const float* c2w1   = (const float*)d_in[10];
  const float* c2b1   = (const float*)d_in[11];
  const float* c2w2   = (const float*)d_in[12];
  const float* c2b2   = (const float*)d_in[13];
  const float* c2root = (const float*)d_in[14];
  const float* c2bias = (const float*)d_in[15];
  const float* fc1w   = (const float*)d_in[16];
  const float* fc1b   = (const float*)d_in[17];
  const float* outw   = (const float*)d_in[18];
  const float* outb   = (const float*)d_in[19];
  float* out = (float*)d_out;

  float*   agg1   = (float*)d_ws;                       // 12.8 MB
  __bf16*  h1b    = (__bf16*)(agg1 + NNODES * H1C);     // 6.4 MB
  float*   agg2   = (float*)(h1b + NNODES * H1C);       // 6.4 MB
  float*   pooled = agg2 + NNODES * H2C;                // 320 KB
  __bf16*  B2s    = (__bf16*)(pooled + NGRAPHS * H2C);  // 32 KB
  __bf16*  B1s    = B2s + 32 * 64 * 8;                  // 24 KB
  int*     cnt    = (int*)(B1s + 2 * 12 * 64 * 8);      // 400 KB
  int*     slots  = cnt + NNODES;                       // 16 MB

  size_t need = (size_t)((char*)(slots + (size_t)NNODES * MAXDEG) - (char*)d_ws);
  bool use_gather = ws_size >= need;

  hipMemsetAsync(pooled, 0, NGRAPHS * H2C * sizeof(float), stream);
  if (use_gather) hipMemsetAsync(cnt, 0, NNODES * sizeof(int), stream);

  k_init1<<<(NNODES * H1C + 255) / 256, 256, 0, stream>>>(x, c1root, c1bias, agg1);
  k_prepB1<<<48, 256, 0, stream>>>(c1w2, c1b2, B1s);
  k_prepB2<<<64, 256, 0, stream>>>(c2w2, B2s);
  k_edge1_mfma<<<NEDGES / 256, 256, 0, stream>>>(x, ei, ea, c1w1, c1b1, B1s, agg1,
      use_gather ? cnt : (int*)nullptr, use_gather ? slots : (int*)nullptr);
  k_mid<<<(NNODES * H2C + 255) / 256, 256, 0, stream>>>(agg1, c2root, c2bias, h1b, agg2);
  if (use_gather) {
    k_gather2<<<(NNODES + NPB - 1) / NPB, 256, 0, stream>>>(h1b, ei, ea, c2w1, c2b1,
        B2s, agg2, cnt, slots, batch, pooled);
  } else {
    k_edge2_mfma<<<NEDGES / 256, 256, 0, stream>>>(h1b, ei, ea, c2w1, c2b1, B2s, agg2);
    k_pool<<<(NNODES * H2C + 255) / 256, 256, 0, stream>>>(agg2, batch, pooled);
  }
  k_head<<<(NGRAPHS + 255) / 256, 256, 0, stream>>>(pooled, fc1w, fc1b, outw, outb, out);
}

// Round 7
// 215.252 us; speedup vs baseline: 1.6240x; 1.6240x over previous
//
#include <hip/hip_runtime.h>

#define NNODES 100000
#define NEDGES 800000
#define NGRAPHS 5000
#define FN 11
#define FE 4
#define H1C 32
#define H2C 16

typedef __bf16 bf16x8 __attribute__((ext_vector_type(8)));
typedef float f32x4 __attribute__((ext_vector_type(4)));

// agg1[n,o] = c1_bias[o] + sum_i x[n,i]*c1_root[i,o]
__global__ __launch_bounds__(256) void k_init1(const float* __restrict__ x,
    const float* __restrict__ root, const float* __restrict__ bias,
    float* __restrict__ agg1) {
  int t = blockIdx.x * 256 + threadIdx.x;
  int n = t >> 5, o = t & 31;
  if (n >= NNODES) return;
  float acc = bias[o];
  #pragma unroll
  for (int i = 0; i < FN; i++) acc += x[n * FN + i] * root[i * H1C + o];
  agg1[n * H1C + o] = acc;
}

// Pre-swizzled bf16 B-fragments for conv1 MFMA (verified round 5).
__global__ __launch_bounds__(256) void k_prepB1(const float* __restrict__ w2,
    const float* __restrict__ b2, __bf16* __restrict__ B1s) {
  int t = blockIdx.x * 256 + threadIdx.x;
  if (t >= 2 * 12 * 64 * 8) return;
  int j = t & 7;
  int lane = (t >> 3) & 63;
  int rest = t >> 9;
  int step = rest % 12;
  int ot = rest / 12;
  int q = (lane >> 4) * 8 + j;
  int o = (lane & 15) + ot * 16;
  float v;
  if (step < 11) v = w2[q * (FN * H1C) + step * H1C + o];
  else v = (q < FN) ? b2[q * H1C + o] : 0.f;
  B1s[t] = (__bf16)v;
}

// conv1 edge pass via MFMA (verified round 5; LDS trimmed to 49 KB -> 3 blocks/CU).
__global__ __launch_bounds__(256, 3) void k_edge1_mfma(
    const float* __restrict__ x, const int* __restrict__ ei,
    const float* __restrict__ ea, const float* __restrict__ w1,
    const float* __restrict__ b1, const __bf16* __restrict__ B1s,
    float* __restrict__ agg1) {
  __shared__ __bf16 Bl[12288];          // 24 KB B-frags
  __shared__ __bf16 h_sl[4][256][8];    // 16 KB h slices
  __shared__ __bf16 xs_sl[2][256][8];   // 8 KB xs slices (slices 2,3 are all-zero -> elided)
  __shared__ int s_dst[256];
  int tid = threadIdx.x;
  {
    const int4* s = (const int4*)B1s;   // 1536 int4 total
    int4* d = (int4*)Bl;
    #pragma unroll
    for (int q = 0; q < 6; q++) d[q * 256 + tid] = s[q * 256 + tid];
  }
  int e = blockIdx.x * 256 + tid;   // NEDGES % 256 == 0
  int src = ei[e];
  s_dst[tid] = ei[NEDGES + e];
  float4 a4 = *reinterpret_cast<const float4*>(ea + e * 4);
  float h[32];
  #pragma unroll
  for (int k = 0; k < 32; k++) {
    float v = b1[k] + a4.x * w1[k] + a4.y * w1[32 + k] + a4.z * w1[64 + k] + a4.w * w1[96 + k];
    h[k] = v > 0.f ? v : 0.f;
  }
  #pragma unroll
  for (int s = 0; s < 4; s++) {
    bf16x8 t8;
    #pragma unroll
    for (int j = 0; j < 8; j++) t8[j] = (__bf16)h[s * 8 + j];
    *reinterpret_cast<bf16x8*>(&h_sl[s][tid][0]) = t8;
  }
  float xsv[FN];
  #pragma unroll
  for (int i = 0; i < FN; i++) xsv[i] = x[src * FN + i];
  #pragma unroll
  for (int s = 0; s < 2; s++) {
    bf16x8 t8;
    #pragma unroll
    for (int j = 0; j < 8; j++) {
      int k = s * 8 + j;
      t8[j] = (k < FN) ? (__bf16)xsv[k] : (__bf16)0.f;
    }
    *reinterpret_cast<bf16x8*>(&xs_sl[s][tid][0]) = t8;
  }
  __syncthreads();
  int lane = tid & 63;
  int w = tid >> 6;
  int halfk = lane >> 4;
  int er = lane & 15;
  #pragma unroll 1
  for (int g = 0; g < 4; g++) {
    int eb = w * 64 + g * 16;
    int el = eb + er;
    bf16x8 hs8 = *reinterpret_cast<const bf16x8*>(&h_sl[halfk][el][0]);
    bf16x8 xs8;
    if (halfk < 2) xs8 = *reinterpret_cast<const bf16x8*>(&xs_sl[halfk][el][0]);
    else xs8 = bf16x8{};   // K rows 16..31 of the bias step are zero
    float hsf[8];
    #pragma unroll
    for (int j = 0; j < 8; j++) hsf[j] = (float)hs8[j];
    f32x4 acc0 = {0.f, 0.f, 0.f, 0.f};
    f32x4 acc1 = {0.f, 0.f, 0.f, 0.f};
    {
      bf16x8 b0 = *reinterpret_cast<const bf16x8*>(&Bl[11 * 512 + lane * 8]);
      bf16x8 b1f = *reinterpret_cast<const bf16x8*>(&Bl[6144 + 11 * 512 + lane * 8]);
      acc0 = __builtin_amdgcn_mfma_f32_16x16x32_bf16(xs8, b0, acc0, 0, 0, 0);
      acc1 = __builtin_amdgcn_mfma_f32_16x16x32_bf16(xs8, b1f, acc1, 0, 0, 0);
    }
    #pragma unroll
    for (int i = 0; i < FN; i++) {
      float xscal = (float)xs_sl[i >> 3][el][i & 7];
      bf16x8 af;
      #pragma unroll
      for (int j = 0; j < 8; j++) af[j] = (__bf16)(xscal * hsf[j]);
      bf16x8 b0 = *reinterpret_cast<const bf16x8*>(&Bl[i * 512 + lane * 8]);
      bf16x8 b1f = *reinterpret_cast<const bf16x8*>(&Bl[6144 + i * 512 + lane * 8]);
      acc0 = __builtin_amdgcn_mfma_f32_16x16x32_bf16(af, b0, acc0, 0, 0, 0);
      acc1 = __builtin_amdgcn_mfma_f32_16x16x32_bf16(af, b1f, acc1, 0, 0, 0);
    }
    #pragma unroll
    for (int r = 0; r < 4; r++) {
      int d = s_dst[eb + halfk * 4 + r];
      atomicAdd(&agg1[d * H1C + er], acc0[r]);
      atomicAdd(&agg1[d * H1C + er + 16], acc1[r]);
    }
  }
}

// h1b = bf16(relu(agg1)); agg2[n,o] = c2_bias[o] + sum_i relu(agg1)[n,i]*c2_root[i,o]
__global__ __launch_bounds__(256) void k_mid(const float* __restrict__ agg1,
    const float* __restrict__ root2, const float* __restrict__ bias2,
    __bf16* __restrict__ h1b, float* __restrict__ agg2) {
  int t = blockIdx.x * 256 + threadIdx.x;
  int n = t >> 4, o = t & 15;
  if (n >= NNODES) return;
  float hv[32];
  #pragma unroll
  for (int i = 0; i < 32; i++) {
    float v = agg1[n * H1C + i];
    hv[i] = v > 0.f ? v : 0.f;
  }
  h1b[n * H1C + o] = (__bf16)hv[o];
  h1b[n * H1C + o + 16] = (__bf16)hv[o + 16];
  float acc = bias2[o];
  #pragma unroll
  for (int i = 0; i < 32; i++) acc += hv[i] * root2[i * H2C + o];
  agg2[n * H2C + o] = acc;
}

// Pre-swizzled bf16 B-fragments for conv2 MFMA (verified round 4).
__global__ __launch_bounds__(256) void k_prepB2(const float* __restrict__ w2,
    __bf16* __restrict__ B2s) {
  int t = blockIdx.x * 256 + threadIdx.x;
  if (t >= 32 * 64 * 8) return;
  int kk = t >> 9;
  int l = (t >> 3) & 63;
  int j = t & 7;
  int i = (l >> 4) * 8 + j;
  int o = l & 15;
  B2s[t] = (__bf16)w2[(kk * 32 + i) * H2C + o];
}

// conv2 edge pass via MFMA (verified round 4; bf16 h_lds + conflict-free
// staging -> 51 KB LDS, 3 blocks/CU).
__global__ __launch_bounds__(256, 3) void k_edge2_mfma(
    const __bf16* __restrict__ h1b, const int* __restrict__ ei,
    const float* __restrict__ ea, const float* __restrict__ w1,
    const float* __restrict__ b1, const __bf16* __restrict__ B2s,
    float* __restrict__ agg2) {
  __shared__ __bf16 Bl[32 * 64 * 8];     // 32 KB
  __shared__ __bf16 h_lds[256][34];      // 17 KB (pad 34: conflict-free scalar reads)
  __shared__ int s_src[256];
  __shared__ int s_dst[256];
  int tid = threadIdx.x;
  {
    const int4* s = (const int4*)B2s;    // 2048 int4
    int4* d = (int4*)Bl;
    #pragma unroll
    for (int q = 0; q < 8; q++) d[q * 256 + tid] = s[q * 256 + tid];
  }
  int e = blockIdx.x * 256 + tid;
  s_src[tid] = ei[e];
  s_dst[tid] = ei[NEDGES + e];
  float4 a4 = *reinterpret_cast<const float4*>(ea + e * 4);
  #pragma unroll
  for (int k = 0; k < 32; k++) {
    float v = b1[k] + a4.x * w1[k] + a4.y * w1[32 + k] + a4.z * w1[64 + k] + a4.w * w1[96 + k];
    h_lds[tid][k] = (__bf16)(v > 0.f ? v : 0.f);
  }
  __syncthreads();
  int lane = tid & 63;
  int w = tid >> 6;
  int halfk = lane >> 4;
  int er = lane & 15;
  #pragma unroll 1
  for (int g = 0; g < 4; g++) {
    int eb = w * 64 + g * 16;
    int el = eb + er;
    int sn = s_src[el];
    bf16x8 hsb = *reinterpret_cast<const bf16x8*>(h1b + sn * H1C + halfk * 8);
    float hsf[8];
    #pragma unroll
    for (int j = 0; j < 8; j++) hsf[j] = (float)hsb[j];
    f32x4 acc = {0.f, 0.f, 0.f, 0.f};
    #pragma unroll
    for (int kk = 0; kk < 32; kk++) {
      float hscal = (float)h_lds[el][kk];
      bf16x8 bfrag = *reinterpret_cast<const bf16x8*>(Bl + (kk * 64 + lane) * 8);
      bf16x8 afrag;
      #pragma unroll
      for (int j = 0; j < 8; j++) afrag[j] = (__bf16)(hscal * hsf[j]);
      acc = __builtin_amdgcn_mfma_f32_16x16x32_bf16(afrag, bfrag, acc, 0, 0, 0);
    }
    #pragma unroll
    for (int r = 0; r < 4; r++) {
      int row = halfk * 4 + r;
      int d = s_dst[eb + row];
      atomicAdd(&agg2[d * H2C + er], acc[r]);
    }
  }
}

// pooled[batch[n],o] += relu(agg2[n,o])
__global__ __launch_bounds__(256) void k_pool(const float* __restrict__ agg2,
    const int* __restrict__ batch, float* __restrict__ pooled) {
  int t = blockIdx.x * 256 + threadIdx.x;
  int n = t >> 4, o = t & 15;
  if (n >= NNODES) return;
  float v = agg2[n * H2C + o];
  v = v > 0.f ? v : 0.f;
  atomicAdd(&pooled[batch[n] * H2C + o], v);
}

// out[g] = relu(pooled[g]@fc1_w + fc1_b) @ out_w + out_b
__global__ __launch_bounds__(256) void k_head(const float* __restrict__ pooled,
    const float* __restrict__ fc1w, const float* __restrict__ fc1b,
    const float* __restrict__ outw, const float* __restrict__ outb,
    float* __restrict__ out) {
  int g = blockIdx.x * 256 + threadIdx.x;
  if (g >= NGRAPHS) return;
  float p[H2C];
  #pragma unroll
  for (int i = 0; i < H2C; i++) p[i] = pooled[g * H2C + i];
  float acc = outb[0];
  #pragma unroll
  for (int o = 0; o < H1C; o++) {
    float v = fc1b[o];
    #pragma unroll
    for (int i = 0; i < H2C; i++) v += p[i] * fc1w[i * H1C + o];
    v = v > 0.f ? v : 0.f;
    acc += v * outw[o];
  }
  out[g] = acc;
}

extern "C" void kernel_launch(void* const* d_in, const int* in_sizes, int n_in,
                              void* d_out, int out_size, void* d_ws, size_t ws_size,
                              hipStream_t stream) {
  const float* x      = (const float*)d_in[0];
  const int*   ei     = (const int*)d_in[1];
  const float* ea     = (const float*)d_in[2];
  const int*   batch  = (const int*)d_in[3];
  const float* c1w1   = (const float*)d_in[4];
  const float* c1b1   = (const float*)d_in[5];
  const float* c1w2   = (const float*)d_in[6];
  const float* c1b2   = (const float*)d_in[7];
  const float* c1root = (const float*)d_in[8];
  const float* c1bias = (const float*)d_in[9];
  const float* c2w1   = (const float*)d_in[10];
  const float* c2b1   = (const float*)d_in[11];
  const float* c2w2   = (const float*)d_in[12];
  const float* c2b2   = (const float*)d_in[13];
  const float* c2root = (const float*)d_in[14];
  const float* c2bias = (const float*)d_in[15];
  const float* fc1w   = (const float*)d_in[16];
  const float* fc1b   = (const float*)d_in[17];
  const float* outw   = (const float*)d_in[18];
  const float* outb   = (const float*)d_in[19];
  float* out = (float*)d_out;

  float*   agg1   = (float*)d_ws;                       // 12.8 MB
  __bf16*  h1b    = (__bf16*)(agg1 + NNODES * H1C);     // 6.4 MB
  float*   agg2   = (float*)(h1b + NNODES * H1C);       // 6.4 MB
  float*   pooled = agg2 + NNODES * H2C;                // 320 KB
  __bf16*  B2s    = (__bf16*)(pooled + NGRAPHS * H2C);  // 32 KB
  __bf16*  B1s    = B2s + 32 * 64 * 8;                  // 24 KB

  hipMemsetAsync(pooled, 0, NGRAPHS * H2C * sizeof(float), stream);

  k_init1<<<(NNODES * H1C + 255) / 256, 256, 0, stream>>>(x, c1root, c1bias, agg1);
  k_prepB1<<<48, 256, 0, stream>>>(c1w2, c1b2, B1s);
  k_prepB2<<<64, 256, 0, stream>>>(c2w2, B2s);
  k_edge1_mfma<<<NEDGES / 256, 256, 0, stream>>>(x, ei, ea, c1w1, c1b1, B1s, agg1);
  k_mid<<<(NNODES * H2C + 255) / 256, 256, 0, stream>>>(agg1, c2root, c2bias, h1b, agg2);
  k_edge2_mfma<<<NEDGES / 256, 256, 0, stream>>>(h1b, ei, ea, c2w1, c2b1, B2s, agg2);
  k_pool<<<(NNODES * H2C + 255) / 256, 256, 0, stream>>>(agg2, batch, pooled);
  k_head<<<(NGRAPHS + 255) / 256, 256, 0, stream>>>(pooled, fc1w, fc1b, outw, outb, out);
}